// Round 1
// baseline (1417.940 us; speedup 1.0000x reference)
//
#include <hip/hip_runtime.h>
#include <math.h>

#define C1F 1.0e-4f   // 0.01^2
#define C2F 9.0e-4f   // 0.03^2

// acc layout: per scale i (0..3), base = i*8
//  +0: sum |left_est - lpy|      +1: sum |right_est - rpy|
//  +2: sum |rl_disp - dl|        +3: sum |lr_disp - dr|
//  +4: sum ssim_l (clipped)      +5: sum ssim_r
//  +6: sum x-grad smooth (dl+dr) +7: sum y-grad smooth (dl+dr)

__device__ __forceinline__ void warp_coeffs(float px, int W, int& i0, int& i1,
                                            float& w0, float& w1) {
    float x0f = floorf(px);
    float f = px - x0f;
    int x0i = (int)x0f;
    int x1i = x0i + 1;
    float v0 = (x0i >= 0 && x0i < W) ? 1.f : 0.f;
    float v1 = (x1i >= 0 && x1i < W) ? 1.f : 0.f;
    i0 = min(max(x0i, 0), W - 1);
    i1 = min(max(x1i, 0), W - 1);
    w0 = v0 * (1.f - f);
    w1 = v1 * f;
}

template<int N>
__device__ __forceinline__ void block_acc(const float* vals, float* gacc) {
    __shared__ float sacc[N];
    if (threadIdx.x < N) sacc[threadIdx.x] = 0.f;
    __syncthreads();
#pragma unroll
    for (int k = 0; k < N; ++k) {
        float v = vals[k];
#pragma unroll
        for (int off = 32; off > 0; off >>= 1) v += __shfl_down(v, off, 64);
        if ((threadIdx.x & 63) == 0) atomicAdd(&sacc[k], v);
    }
    __syncthreads();
    if (threadIdx.x < N) atomicAdd(&gacc[threadIdx.x], sacc[threadIdx.x]);
}

__global__ void k_zero(float* acc) {
    if (threadIdx.x < 64) acc[threadIdx.x] = 0.f;
}

// Bilinear align-corners resize of left+right full-res images to (oh, ow).
__global__ void k_resize(const float* __restrict__ left, const float* __restrict__ right,
                         float* __restrict__ lo, float* __restrict__ ro,
                         int B, int H, int W, int oh, int ow) {
    long long idx = (long long)blockIdx.x * blockDim.x + threadIdx.x;
    long long total = (long long)B * 3 * oh * ow;
    if (idx >= 2 * total) return;
    const float* src = left;
    float* dst = lo;
    if (idx >= total) { src = right; dst = ro; idx -= total; }
    int x = (int)(idx % ow);
    long long t = idx / ow;
    int y = (int)(t % oh);
    t /= oh;
    int c = (int)(t % 3);
    int b = (int)(t / 3);
    float sy = (float)(H - 1) / (float)(oh - 1);
    float sx = (float)(W - 1) / (float)(ow - 1);
    float fy = y * sy;
    float fx = x * sx;
    int y0 = (int)floorf(fy); float wy = fy - (float)y0;
    int x0 = (int)floorf(fx); float wx = fx - (float)x0;
    int y1 = min(y0 + 1, H - 1); y0 = min(y0, H - 1);
    int x1 = min(x0 + 1, W - 1); x0 = min(x0, W - 1);
    const float* p = src + (((long long)b * 3 + c) * H) * W;
    float a00 = p[(long long)y0 * W + x0];
    float a10 = p[(long long)y1 * W + x0];
    float a01 = p[(long long)y0 * W + x1];
    float a11 = p[(long long)y1 * W + x1];
    float r0 = a00 * (1.f - wy) + a10 * wy;
    float r1 = a01 * (1.f - wy) + a11 * wy;
    dst[(((long long)b * 3 + c) * oh + y) * ow + x] = r0 * (1.f - wx) + r1 * wx;
}

// Per-pixel: warp L1 (both sides) + LR-consistency terms.
__global__ void k_warp_l1(const float* __restrict__ disp, const float* __restrict__ lpy,
                          const float* __restrict__ rpy, float* __restrict__ acc,
                          int B, int h, int w) {
    long long idx = (long long)blockIdx.x * blockDim.x + threadIdx.x;
    long long total = (long long)B * h * w;
    float sums[4] = {0.f, 0.f, 0.f, 0.f};
    if (idx < total) {
        int x = (int)(idx % w);
        int y = (int)((idx / w) % h);
        int b = (int)(idx / ((long long)w * h));
        const float* dl_row = disp + (((long long)b * 2 + 0) * h + y) * w;
        const float* dr_row = disp + (((long long)b * 2 + 1) * h + y) * w;
        float dl = dl_row[x], dr = dr_row[x];
        float invWm1 = 1.f / (float)(w - 1);
        float xb = (float)x * invWm1;
        int i0, i1; float w0, w1;
        // left_est = warp(rpy, dl, -1); rl_disp = warp(dr, dl, -1)
        warp_coeffs((xb - dl) * (float)(w - 1), w, i0, i1, w0, w1);
#pragma unroll
        for (int c = 0; c < 3; ++c) {
            const float* rrow = rpy + (((long long)b * 3 + c) * h + y) * w;
            const float* lrow = lpy + (((long long)b * 3 + c) * h + y) * w;
            float le = rrow[i0] * w0 + rrow[i1] * w1;
            sums[0] += fabsf(le - lrow[x]);
        }
        float rl = dr_row[i0] * w0 + dr_row[i1] * w1;
        sums[2] += fabsf(rl - dl);
        // right_est = warp(lpy, dr, +1); lr_disp = warp(dl, dr, +1)
        warp_coeffs((xb + dr) * (float)(w - 1), w, i0, i1, w0, w1);
#pragma unroll
        for (int c = 0; c < 3; ++c) {
            const float* rrow = rpy + (((long long)b * 3 + c) * h + y) * w;
            const float* lrow = lpy + (((long long)b * 3 + c) * h + y) * w;
            float re = lrow[i0] * w0 + lrow[i1] * w1;
            sums[1] += fabsf(re - rrow[x]);
        }
        float lr = dl_row[i0] * w0 + dl_row[i1] * w1;
        sums[3] += fabsf(lr - dr);
    }
    block_acc<4>(sums, acc);   // slots base+0..3
}

// SSIM over 3x3 valid windows, warps recomputed inline; both sides, 3 channels.
__global__ void k_ssim(const float* __restrict__ disp, const float* __restrict__ lpy,
                       const float* __restrict__ rpy, float* __restrict__ acc,
                       int B, int h, int w) {
    int ho = h - 2, wo = w - 2;
    long long idx = (long long)blockIdx.x * blockDim.x + threadIdx.x;
    long long total = (long long)B * ho * wo;
    float sums[2] = {0.f, 0.f};
    if (idx < total) {
        int xo = (int)(idx % wo);
        int yo = (int)((idx / wo) % ho);
        int b = (int)(idx / ((long long)wo * ho));
        float invWm1 = 1.f / (float)(w - 1);
        float sLx[3] = {0,0,0}, sLy[3] = {0,0,0}, sLxx[3] = {0,0,0}, sLyy[3] = {0,0,0}, sLxy[3] = {0,0,0};
        float sRx[3] = {0,0,0}, sRy[3] = {0,0,0}, sRxx[3] = {0,0,0}, sRyy[3] = {0,0,0}, sRxy[3] = {0,0,0};
#pragma unroll
        for (int dy = 0; dy < 3; ++dy) {
            int y = yo + dy;
            const float* dl_row = disp + (((long long)b * 2 + 0) * h + y) * w;
            const float* dr_row = disp + (((long long)b * 2 + 1) * h + y) * w;
#pragma unroll
            for (int dx = 0; dx < 3; ++dx) {
                int x = xo + dx;
                float dl = dl_row[x], dr = dr_row[x];
                float xb = (float)x * invWm1;
                int i0L, i1L; float w0L, w1L;
                warp_coeffs((xb - dl) * (float)(w - 1), w, i0L, i1L, w0L, w1L);
                int i0R, i1R; float w0R, w1R;
                warp_coeffs((xb + dr) * (float)(w - 1), w, i0R, i1R, w0R, w1R);
#pragma unroll
                for (int c = 0; c < 3; ++c) {
                    const float* lrow = lpy + (((long long)b * 3 + c) * h + y) * w;
                    const float* rrow = rpy + (((long long)b * 3 + c) * h + y) * w;
                    float le = rrow[i0L] * w0L + rrow[i1L] * w1L;  // x (left side)
                    float lv = lrow[x];                            // y (left side)
                    sLx[c] += le; sLy[c] += lv;
                    sLxx[c] += le * le; sLyy[c] += lv * lv; sLxy[c] += le * lv;
                    float re = lrow[i0R] * w0R + lrow[i1R] * w1R;  // x (right side)
                    float rv = rrow[x];                            // y (right side)
                    sRx[c] += re; sRy[c] += rv;
                    sRxx[c] += re * re; sRyy[c] += rv * rv; sRxy[c] += re * rv;
                }
            }
        }
        const float inv9 = 1.f / 9.f;
#pragma unroll
        for (int c = 0; c < 3; ++c) {
            {
                float mx = sLx[c] * inv9, my = sLy[c] * inv9;
                float vx = sLxx[c] * inv9 - mx * mx;
                float vy = sLyy[c] * inv9 - my * my;
                float vxy = sLxy[c] * inv9 - mx * my;
                float s = (2.f * mx * my + C1F) * (2.f * vxy + C2F) /
                          ((mx * mx + my * my + C1F) * (vx + vy + C2F));
                float v = (1.f - s) * 0.5f;
                sums[0] += fminf(fmaxf(v, 0.f), 1.f);
            }
            {
                float mx = sRx[c] * inv9, my = sRy[c] * inv9;
                float vx = sRxx[c] * inv9 - mx * mx;
                float vy = sRyy[c] * inv9 - my * my;
                float vxy = sRxy[c] * inv9 - mx * my;
                float s = (2.f * mx * my + C1F) * (2.f * vxy + C2F) /
                          ((mx * mx + my * my + C1F) * (vx + vy + C2F));
                float v = (1.f - s) * 0.5f;
                sums[1] += fminf(fmaxf(v, 0.f), 1.f);
            }
        }
    }
    block_acc<2>(sums, acc + 4);   // slots base+4,5
}

// Edge-aware smoothness, both disparities.
__global__ void k_smooth(const float* __restrict__ disp, const float* __restrict__ lpy,
                         const float* __restrict__ rpy, float* __restrict__ acc,
                         int B, int h, int w) {
    long long idx = (long long)blockIdx.x * blockDim.x + threadIdx.x;
    long long total = (long long)B * h * w;
    float sums[2] = {0.f, 0.f};
    if (idx < total) {
        int x = (int)(idx % w);
        int y = (int)((idx / w) % h);
        int b = (int)(idx / ((long long)w * h));
        const float* dl_row = disp + (((long long)b * 2 + 0) * h + y) * w;
        const float* dr_row = disp + (((long long)b * 2 + 1) * h + y) * w;
        const float third = 1.f / 3.f;
        if (x < w - 1) {
            float dgl = dl_row[x] - dl_row[x + 1];
            float dgr = dr_row[x] - dr_row[x + 1];
            float al = 0.f, ar = 0.f;
#pragma unroll
            for (int c = 0; c < 3; ++c) {
                const float* lrow = lpy + (((long long)b * 3 + c) * h + y) * w;
                const float* rrow = rpy + (((long long)b * 3 + c) * h + y) * w;
                al += fabsf(lrow[x] - lrow[x + 1]);
                ar += fabsf(rrow[x] - rrow[x + 1]);
            }
            sums[0] += fabsf(dgl * expf(-al * third)) + fabsf(dgr * expf(-ar * third));
        }
        if (y < h - 1) {
            float dgl = dl_row[x] - dl_row[x + w];
            float dgr = dr_row[x] - dr_row[x + w];
            float al = 0.f, ar = 0.f;
#pragma unroll
            for (int c = 0; c < 3; ++c) {
                const float* lrow = lpy + (((long long)b * 3 + c) * h + y) * w;
                const float* rrow = rpy + (((long long)b * 3 + c) * h + y) * w;
                al += fabsf(lrow[x] - lrow[x + w]);
                ar += fabsf(rrow[x] - rrow[x + w]);
            }
            sums[1] += fabsf(dgl * expf(-al * third)) + fabsf(dgr * expf(-ar * third));
        }
    }
    block_acc<2>(sums, acc + 6);   // slots base+6,7
}

__global__ void k_final(const float* __restrict__ acc, float* __restrict__ out,
                        int B, int H, int W) {
    if (threadIdx.x != 0 || blockIdx.x != 0) return;
    float img = 0.f, lr = 0.f, sm = 0.f;
    for (int i = 0; i < 4; ++i) {
        int r = 1 << i;
        int h = H / r, w = W / r;
        const float* a = acc + i * 8;
        float Nl1 = (float)B * 3.f * (float)h * (float)w;
        float Nss = (float)B * 3.f * (float)(h - 2) * (float)(w - 2);
        float Nlr = (float)B * (float)h * (float)w;
        float Nsx = (float)B * (float)h * (float)(w - 1);
        float Nsy = (float)B * (float)(h - 1) * (float)w;
        img += 0.5f * (a[4] / Nss) + 0.5f * (a[0] / Nl1)
             + 0.5f * (a[5] / Nss) + 0.5f * (a[1] / Nl1);
        lr += a[2] / Nlr + a[3] / Nlr;
        sm += (a[6] / Nsx + a[7] / Nsy) / (float)r;
    }
    out[0] = img + 0.1f * sm + 1.0f * lr;
}

extern "C" void kernel_launch(void* const* d_in, const int* in_sizes, int n_in,
                              void* d_out, int out_size, void* d_ws, size_t ws_size,
                              hipStream_t stream) {
    const int B = 16, H = 384, W = 768;
    const float* disp[4] = {(const float*)d_in[0], (const float*)d_in[1],
                            (const float*)d_in[2], (const float*)d_in[3]};
    const float* left = (const float*)d_in[4];
    const float* right = (const float*)d_in[5];
    float* out = (float*)d_out;

    float* acc = (float*)d_ws;
    float* pyr = acc + 256;
    // pyramid buffers for scales 1..3 (left & right)
    long long sz1 = (long long)B * 3 * (H / 2) * (W / 2);
    long long sz2 = (long long)B * 3 * (H / 4) * (W / 4);
    long long sz3 = (long long)B * 3 * (H / 8) * (W / 8);
    float* lp1 = pyr;
    float* rp1 = lp1 + sz1;
    float* lp2 = rp1 + sz1;
    float* rp2 = lp2 + sz2;
    float* lp3 = rp2 + sz2;
    float* rp3 = lp3 + sz3;

    const int TB = 256;
    hipLaunchKernelGGL(k_zero, dim3(1), dim3(64), 0, stream, acc);

    // build pyramids
    {
        long long t1 = 2 * sz1, t2 = 2 * sz2, t3 = 2 * sz3;
        hipLaunchKernelGGL(k_resize, dim3((unsigned)((t1 + TB - 1) / TB)), dim3(TB), 0, stream,
                           left, right, lp1, rp1, B, H, W, H / 2, W / 2);
        hipLaunchKernelGGL(k_resize, dim3((unsigned)((t2 + TB - 1) / TB)), dim3(TB), 0, stream,
                           left, right, lp2, rp2, B, H, W, H / 4, W / 4);
        hipLaunchKernelGGL(k_resize, dim3((unsigned)((t3 + TB - 1) / TB)), dim3(TB), 0, stream,
                           left, right, lp3, rp3, B, H, W, H / 8, W / 8);
    }

    const float* lp[4] = {left, lp1, lp2, lp3};
    const float* rp[4] = {right, rp1, rp2, rp3};
    for (int i = 0; i < 4; ++i) {
        int r = 1 << i;
        int h = H / r, w = W / r;
        long long np = (long long)B * h * w;
        long long ns = (long long)B * (h - 2) * (w - 2);
        float* a = acc + i * 8;
        hipLaunchKernelGGL(k_warp_l1, dim3((unsigned)((np + TB - 1) / TB)), dim3(TB), 0, stream,
                           disp[i], lp[i], rp[i], a, B, h, w);
        hipLaunchKernelGGL(k_ssim, dim3((unsigned)((ns + TB - 1) / TB)), dim3(TB), 0, stream,
                           disp[i], lp[i], rp[i], a, B, h, w);
        hipLaunchKernelGGL(k_smooth, dim3((unsigned)((np + TB - 1) / TB)), dim3(TB), 0, stream,
                           disp[i], lp[i], rp[i], a, B, h, w);
    }
    hipLaunchKernelGGL(k_final, dim3(1), dim3(64), 0, stream, acc, out, B, H, W);
}